// Round 1
// baseline (376.896 us; speedup 1.0000x reference)
//
#include <hip/hip_runtime.h>

#define BATCH  8192
#define NFEAT  2048
#define NFIELD 8
#define NFACT  64
#define FDIM   256      // features per field
#define NPAIR  36       // unordered field pairs incl. diagonal

#define BM 64           // batch rows per block (pair kernel)
#define KC 64           // K-chunk
#define XPAD 4          // Xs/Xt row stride = KC+XPAD = 68 words (16B-aligned, 2-way bank alias only)

// ---------------------------------------------------------------------------
// K0: sv[i] = sum_l V[i, feat2field[i], l]^2
// ---------------------------------------------------------------------------
__global__ void sv_kernel(const float* __restrict__ V, const int* __restrict__ f2f,
                          float* __restrict__ sv) {
    int i = blockIdx.x * blockDim.x + threadIdx.x;
    if (i >= NFEAT) return;
    int f = f2f[i];
    const float* vp = V + (size_t)i * (NFIELD * NFACT) + (size_t)f * NFACT;
    float s = 0.f;
#pragma unroll
    for (int l = 0; l < NFACT; l += 4) {
        float4 v = *reinterpret_cast<const float4*>(vp + l);
        s += v.x * v.x + v.y * v.y + v.z * v.z + v.w * v.w;
    }
    sv[i] = s;
}

// ---------------------------------------------------------------------------
// K1: out[row] = b0 + x[row]·w - 0.25 * sum_i x^2 * sv[i]
// One block (256 threads) per batch row. Initializes d_out (it is poisoned
// before every call) so the pair kernel can atomicAdd into it.
// ---------------------------------------------------------------------------
__global__ void base_kernel(const float* __restrict__ x, const float* __restrict__ bptr,
                            const float* __restrict__ w, const float* __restrict__ sv,
                            float* __restrict__ out) {
    const int row = blockIdx.x;
    const int tid = threadIdx.x;
    const float* xr = x + (size_t)row * NFEAT;

    float lin = 0.f, q = 0.f;
#pragma unroll
    for (int j = 0; j < 2; ++j) {
        int idx = j * 1024 + tid * 4;           // coalesced float4
        float4 xv = *reinterpret_cast<const float4*>(xr + idx);
        float4 wv = *reinterpret_cast<const float4*>(w + idx);
        float4 sq = *reinterpret_cast<const float4*>(sv + idx);
        lin += xv.x * wv.x + xv.y * wv.y + xv.z * wv.z + xv.w * wv.w;
        q   += xv.x * xv.x * sq.x + xv.y * xv.y * sq.y
             + xv.z * xv.z * sq.z + xv.w * xv.w * sq.w;
    }
    // wave reduce (64 lanes)
#pragma unroll
    for (int off = 32; off >= 1; off >>= 1) {
        lin += __shfl_down(lin, off, 64);
        q   += __shfl_down(q, off, 64);
    }
    __shared__ float slin[4], sq4[4];
    const int wave = tid >> 6;
    if ((tid & 63) == 0) { slin[wave] = lin; sq4[wave] = q; }
    __syncthreads();
    if (tid == 0) {
        float L = slin[0] + slin[1] + slin[2] + slin[3];
        float Q = sq4[0] + sq4[1] + sq4[2] + sq4[3];
        out[row] = bptr[0] + L - 0.25f * Q;
    }
}

// ---------------------------------------------------------------------------
// K2: for field pair (s,t):
//   A[r][l] = sum_{k in field s} x[r, s*256+k] * V[s*256+k, t, l]   (= M[r,s,t,l])
//   B[r][l] = sum_{k in field t} x[r, t*256+k] * V[t*256+k, s, l]   (= M[r,t,s,l])
//   out[r] += (s==t ? 0.25 : 0.5) * sum_l A[r][l]*B[r][l]
// Grid: (BATCH/BM tiles, 36 pairs). Block 256 threads.
// Per thread: 4 rows x 4 l-cols, two sides -> 32 fp32 accumulators.
// ---------------------------------------------------------------------------
__global__ __launch_bounds__(256) void pair_kernel(const float* __restrict__ x,
                                                   const float* __restrict__ V,
                                                   float* __restrict__ out) {
    __shared__ float Xs[BM][KC + XPAD];
    __shared__ float Xt[BM][KC + XPAD];
    __shared__ float Vs[KC][NFACT];
    __shared__ float Vt[KC][NFACT];

    const int tile = blockIdx.x;
    // pair index -> (s, t), s <= t
    int p = blockIdx.y;
    int s = 0;
    while (p >= NFIELD - s) { p -= NFIELD - s; ++s; }
    const int t = s + p;
    const bool diag = (s == t);

    const int tid  = threadIdx.x;
    const int lgrp = tid & 15;   // l-group: cols l0..l0+3
    const int rgrp = tid >> 4;   // row-group: rows r0..r0+3
    const int l0 = lgrp * 4;
    const int r0 = rgrp * 4;
    const int rowBase = tile * BM;

    float accA[4][4] = {};
    float accB[4][4] = {};

    for (int kc = 0; kc < FDIM; kc += KC) {
        __syncthreads();   // protect LDS reuse across chunks
        // ---- stage X tiles: 64 rows x KC, float4 per thread x 4 passes
#pragma unroll
        for (int it = 0; it < 4; ++it) {
            int rr = (tid >> 4) + it * 16;
            const float* gx = x + (size_t)(rowBase + rr) * NFEAT + s * FDIM + kc + (tid & 15) * 4;
            *reinterpret_cast<float4*>(&Xs[rr][(tid & 15) * 4]) =
                *reinterpret_cast<const float4*>(gx);
            if (!diag) {
                const float* gx2 = x + (size_t)(rowBase + rr) * NFEAT + t * FDIM + kc + (tid & 15) * 4;
                *reinterpret_cast<float4*>(&Xt[rr][(tid & 15) * 4]) =
                    *reinterpret_cast<const float4*>(gx2);
            }
        }
        // ---- stage V chunks: Vs[k][l] = V[s*256+kc+k, t, l]
#pragma unroll
        for (int it = 0; it < 4; ++it) {
            int kk = (tid >> 4) + it * 16;
            const float* gv = V + (size_t)(s * FDIM + kc + kk) * (NFIELD * NFACT) + t * NFACT + (tid & 15) * 4;
            *reinterpret_cast<float4*>(&Vs[kk][(tid & 15) * 4]) =
                *reinterpret_cast<const float4*>(gv);
            if (!diag) {
                const float* gv2 = V + (size_t)(t * FDIM + kc + kk) * (NFIELD * NFACT) + s * NFACT + (tid & 15) * 4;
                *reinterpret_cast<float4*>(&Vt[kk][(tid & 15) * 4]) =
                    *reinterpret_cast<const float4*>(gv2);
            }
        }
        __syncthreads();

        // ---- compute: 16 iterations of 4-k micro-steps
        for (int k = 0; k < KC; k += 4) {
            float xa[4][4], va[4][4];
#pragma unroll
            for (int r = 0; r < 4; ++r) {
                float4 v = *reinterpret_cast<const float4*>(&Xs[r0 + r][k]);
                xa[r][0] = v.x; xa[r][1] = v.y; xa[r][2] = v.z; xa[r][3] = v.w;
            }
#pragma unroll
            for (int kk = 0; kk < 4; ++kk) {
                float4 v = *reinterpret_cast<const float4*>(&Vs[k + kk][l0]);
                va[kk][0] = v.x; va[kk][1] = v.y; va[kk][2] = v.z; va[kk][3] = v.w;
            }
#pragma unroll
            for (int kk = 0; kk < 4; ++kk)
#pragma unroll
                for (int r = 0; r < 4; ++r)
#pragma unroll
                    for (int c = 0; c < 4; ++c)
                        accA[r][c] = fmaf(xa[r][kk], va[kk][c], accA[r][c]);

            if (!diag) {
                float xb[4][4], vb[4][4];
#pragma unroll
                for (int r = 0; r < 4; ++r) {
                    float4 v = *reinterpret_cast<const float4*>(&Xt[r0 + r][k]);
                    xb[r][0] = v.x; xb[r][1] = v.y; xb[r][2] = v.z; xb[r][3] = v.w;
                }
#pragma unroll
                for (int kk = 0; kk < 4; ++kk) {
                    float4 v = *reinterpret_cast<const float4*>(&Vt[k + kk][l0]);
                    vb[kk][0] = v.x; vb[kk][1] = v.y; vb[kk][2] = v.z; vb[kk][3] = v.w;
                }
#pragma unroll
                for (int kk = 0; kk < 4; ++kk)
#pragma unroll
                    for (int r = 0; r < 4; ++r)
#pragma unroll
                        for (int c = 0; c < 4; ++c)
                            accB[r][c] = fmaf(xb[r][kk], vb[kk][c], accB[r][c]);
            }
        }
    }

    // ---- epilogue: per-row dot over this thread's 4 l-cols
    float pr[4];
#pragma unroll
    for (int r = 0; r < 4; ++r) {
        float d = 0.f;
#pragma unroll
        for (int c = 0; c < 4; ++c)
            d += accA[r][c] * (diag ? accA[r][c] : accB[r][c]);
        pr[r] = d;
    }
    // reduce across the 16 lanes (lgrp) sharing this row-group
#pragma unroll
    for (int off = 1; off < 16; off <<= 1) {
#pragma unroll
        for (int r = 0; r < 4; ++r)
            pr[r] += __shfl_xor(pr[r], off, 64);
    }
    if (lgrp == 0) {
        const float scale = diag ? 0.25f : 0.5f;  // 0.25 * (2 for off-diagonal)
#pragma unroll
        for (int r = 0; r < 4; ++r)
            atomicAdd(&out[rowBase + r0 + r], scale * pr[r]);
    }
}

// ---------------------------------------------------------------------------
extern "C" void kernel_launch(void* const* d_in, const int* in_sizes, int n_in,
                              void* d_out, int out_size, void* d_ws, size_t ws_size,
                              hipStream_t stream) {
    const float* x   = (const float*)d_in[0];
    const float* b   = (const float*)d_in[1];
    const float* w   = (const float*)d_in[2];
    const float* V   = (const float*)d_in[3];
    const int*   f2f = (const int*)d_in[4];
    float* out = (float*)d_out;
    float* sv  = (float*)d_ws;   // 2048 floats of scratch

    sv_kernel<<<(NFEAT + 255) / 256, 256, 0, stream>>>(V, f2f, sv);
    base_kernel<<<BATCH, 256, 0, stream>>>(x, b, w, sv, out);
    dim3 grid(BATCH / BM, NPAIR);
    pair_kernel<<<grid, 256, 0, stream>>>(x, V, out);
}

// Round 2
// 180.563 us; speedup vs baseline: 2.0873x; 2.0873x over previous
//
#include <hip/hip_runtime.h>

#define BATCH  8192
#define NFEAT  2048
#define NFIELD 8
#define NFACT  64
#define FDIM   256
#define NPAIR  36

typedef short short8v __attribute__((ext_vector_type(8)));
typedef __bf16 bf16x8 __attribute__((ext_vector_type(8)));
typedef float f32x4 __attribute__((ext_vector_type(4)));

__device__ inline unsigned short f2bf(float f) {
    unsigned int u = __float_as_uint(f);
    unsigned int r = u + 0x7FFF + ((u >> 16) & 1);   // RNE
    return (unsigned short)(r >> 16);
}
__device__ inline float bf2f(unsigned short h) {
    return __uint_as_float(((unsigned int)h) << 16);
}
__device__ inline f32x4 mfma16(bf16x8 a, bf16x8 b, f32x4 c) {
    return __builtin_amdgcn_mfma_f32_16x16x32_bf16(a, b, c, 0, 0, 0);
}

// ---------------------------------------------------------------------------
// sv[i] = ||V[i, f2f[i], :]||^2
// ---------------------------------------------------------------------------
__global__ void sv_kernel(const float* __restrict__ V, const int* __restrict__ f2f,
                          float* __restrict__ sv) {
    int i = blockIdx.x * blockDim.x + threadIdx.x;
    if (i >= NFEAT) return;
    int f = f2f[i];
    const float* vp = V + (size_t)i * (NFIELD * NFACT) + (size_t)f * NFACT;
    float s = 0.f;
#pragma unroll
    for (int l = 0; l < NFACT; l += 4) {
        float4 v = *reinterpret_cast<const float4*>(vp + l);
        s += v.x * v.x + v.y * v.y + v.z * v.z + v.w * v.w;
    }
    sv[i] = s;
}

// ---------------------------------------------------------------------------
// out[i] = b[0]   (d_out is poisoned before every call)
// ---------------------------------------------------------------------------
__global__ void init_out(const float* __restrict__ bptr, float* __restrict__ out) {
    int i = blockIdx.x * blockDim.x + threadIdx.x;
    if (i < BATCH) out[i] = bptr[0];
}

// ---------------------------------------------------------------------------
// Convert V -> bf16 hi/lo, fragment-linear layout:
//   off = ((((s*8+t)*8 + kc)*4 + ct)*64 + lane)*8 + e
//   element = V[i = s*256 + kc*32 + (lane>>4)*8 + e][t][l = ct*16 + (lane&15)]
// ---------------------------------------------------------------------------
__global__ void convert_v(const float* __restrict__ V,
                          unsigned short* __restrict__ vh, unsigned short* __restrict__ vl) {
    const int tid = blockIdx.x * 256 + threadIdx.x;        // 0 .. 131071
    const int lane = tid & 63;
    const int ct = (tid >> 6) & 3;
    const int kc = (tid >> 8) & 7;
    const int t  = (tid >> 11) & 7;
    const int s  = tid >> 14;
    const int l  = ct * 16 + (lane & 15);
    const int i0 = s * 256 + kc * 32 + (lane >> 4) * 8;
    short8v hv, lv;
#pragma unroll
    for (int e = 0; e < 8; ++e) {
        float v = V[(size_t)(i0 + e) * (NFIELD * NFACT) + t * NFACT + l];
        unsigned short h = f2bf(v);
        hv[e] = (short)h;
        lv[e] = (short)f2bf(v - bf2f(h));
    }
    *reinterpret_cast<short8v*>(vh + (size_t)tid * 8) = hv;
    *reinterpret_cast<short8v*>(vl + (size_t)tid * 8) = lv;
}

// ---------------------------------------------------------------------------
// Convert x -> bf16 hi/lo fragment-linear layout, fused with linear + self terms:
//   off = ((((rb*8 + s)*8 + kc)*8 + rt)*64 + lane)*8 + e
//   element = x[row = rb*128 + rt*16 + (lane&15)][col = s*256 + kc*32 + (lane>>4)*8 + e]
//   out[row] += x_row . w  - 0.25 * sum x^2 * sv
// ---------------------------------------------------------------------------
__global__ void convert_x_fused(const float* __restrict__ x, const float* __restrict__ w,
                                const float* __restrict__ sv,
                                unsigned short* __restrict__ xh, unsigned short* __restrict__ xl,
                                float* __restrict__ out) {
    const int tid = blockIdx.x * 256 + threadIdx.x;        // 0 .. 2097151
    const int lane = tid & 63;
    const int rt = (tid >> 6) & 7;
    const int kc = (tid >> 9) & 7;
    const int s  = (tid >> 12) & 7;
    const int rb = tid >> 15;                              // 0..63
    const int row = rb * 128 + rt * 16 + (lane & 15);
    const int col = s * 256 + kc * 32 + (lane >> 4) * 8;

    const float* xp = x + (size_t)row * NFEAT + col;
    float4 a  = *reinterpret_cast<const float4*>(xp);
    float4 b4 = *reinterpret_cast<const float4*>(xp + 4);
    float4 w0 = *reinterpret_cast<const float4*>(w + col);
    float4 w1 = *reinterpret_cast<const float4*>(w + col + 4);
    float4 s0 = *reinterpret_cast<const float4*>(sv + col);
    float4 s1 = *reinterpret_cast<const float4*>(sv + col + 4);

    float xs[8] = {a.x, a.y, a.z, a.w, b4.x, b4.y, b4.z, b4.w};
    float wsv[8] = {w0.x, w0.y, w0.z, w0.w, w1.x, w1.y, w1.z, w1.w};
    float ss[8] = {s0.x, s0.y, s0.z, s0.w, s1.x, s1.y, s1.z, s1.w};

    short8v hv, lv;
    float lin = 0.f, q = 0.f;
#pragma unroll
    for (int e = 0; e < 8; ++e) {
        float v = xs[e];
        unsigned short h = f2bf(v);
        float hf = bf2f(h);
        hv[e] = (short)h;
        lv[e] = (short)f2bf(v - hf);
        lin += v * wsv[e];
        q   += v * v * ss[e];
    }
    *reinterpret_cast<short8v*>(xh + (size_t)tid * 8) = hv;
    *reinterpret_cast<short8v*>(xl + (size_t)tid * 8) = lv;

    float c = lin - 0.25f * q;
    c += __shfl_xor(c, 16, 64);
    c += __shfl_xor(c, 32, 64);
    if ((lane >> 4) == 0) atomicAdd(&out[row], c);
}

// ---------------------------------------------------------------------------
// MFMA pair kernel. BM=128 rows/block, KC=32, 4 waves; wave owns rows
// [wid*32, wid*32+32), all 64 l-cols. 3-way bf16 split: hh + hl + lh.
//   side A = M[row, s, t, :] ;  side B = M[row, t, s, :]
//   out[row] += (diag ? 0.25 : 0.5) * <A_row, B_row>
// LDS layout is fragment-linear (consume order), conflict-free.
// ---------------------------------------------------------------------------
__global__ __launch_bounds__(256, 3) void pair_mfma(
    const unsigned short* __restrict__ xh, const unsigned short* __restrict__ xl,
    const unsigned short* __restrict__ vh, const unsigned short* __restrict__ vl,
    float* __restrict__ out) {
    __shared__ unsigned short lds[24576];   // 48 KB
    // element offsets: X arrays 4096 each (8 rt * 512): XHS=0, XLS=4096, XHT=8192, XLT=12288
    //                  V arrays 2048 each (4 ct * 512): VHS=16384, VLS=18432, VHT=20480, VLT=22528

    const int tile = blockIdx.x;           // 64 row-tiles of 128
    int p = blockIdx.y;
    int s = 0;
    while (p >= NFIELD - s) { p -= NFIELD - s; ++s; }
    const int t = s + p;
    const bool diag = (s == t);

    const int tid = threadIdx.x, lane = tid & 63, wid = tid >> 6;

    f32x4 accA[2][4] = {};
    f32x4 accB[2][4] = {};

    // staging roles: wid0: xh(field s)+vh(s,t); wid1: xl(s)+vl(s,t);
    //                wid2: xh(t)+vh(t,s);       wid3: xl(t)+vl(t,s)
    const unsigned short* xsrc = (wid & 1) ? xl : xh;
    const unsigned short* vsrc = (wid & 1) ? vl : vh;
    const int f     = (wid < 2) ? s : t;
    const int vpair = (wid < 2) ? (s * 8 + t) : (t * 8 + s);
    const int xdst  = wid * 4096;
    const int vdst  = 16384 + wid * 2048;
    const bool active = !(diag && wid >= 2);

    for (int kc = 0; kc < 8; ++kc) {
        short8v xr[8], vr[4];
        if (active) {
            size_t xb = ((size_t)((tile * 8 + f) * 8 + kc)) * 4096 + lane * 8;
#pragma unroll
            for (int rt = 0; rt < 8; ++rt)
                xr[rt] = *reinterpret_cast<const short8v*>(xsrc + xb + rt * 512);
            size_t vb = ((size_t)(vpair * 8 + kc)) * 2048 + lane * 8;
#pragma unroll
            for (int ct = 0; ct < 4; ++ct)
                vr[ct] = *reinterpret_cast<const short8v*>(vsrc + vb + ct * 512);
        }
        __syncthreads();               // previous chunk's readers done
        if (active) {
#pragma unroll
            for (int rt = 0; rt < 8; ++rt)
                *reinterpret_cast<short8v*>(&lds[xdst + rt * 512 + lane * 8]) = xr[rt];
#pragma unroll
            for (int ct = 0; ct < 4; ++ct)
                *reinterpret_cast<short8v*>(&lds[vdst + ct * 512 + lane * 8]) = vr[ct];
        }
        __syncthreads();               // tile staged

        const int rt0 = wid * 2, rt1 = rt0 + 1;
        bf16x8 ah0 = *reinterpret_cast<const bf16x8*>(&lds[0     + rt0 * 512 + lane * 8]);
        bf16x8 ah1 = *reinterpret_cast<const bf16x8*>(&lds[0     + rt1 * 512 + lane * 8]);
        bf16x8 al0 = *reinterpret_cast<const bf16x8*>(&lds[4096  + rt0 * 512 + lane * 8]);
        bf16x8 al1 = *reinterpret_cast<const bf16x8*>(&lds[4096  + rt1 * 512 + lane * 8]);
#pragma unroll
        for (int ct = 0; ct < 4; ++ct) {
            bf16x8 bh = *reinterpret_cast<const bf16x8*>(&lds[16384 + ct * 512 + lane * 8]);
            bf16x8 bl = *reinterpret_cast<const bf16x8*>(&lds[18432 + ct * 512 + lane * 8]);
            accA[0][ct] = mfma16(ah0, bh, accA[0][ct]);
            accA[0][ct] = mfma16(ah0, bl, accA[0][ct]);
            accA[0][ct] = mfma16(al0, bh, accA[0][ct]);
            accA[1][ct] = mfma16(ah1, bh, accA[1][ct]);
            accA[1][ct] = mfma16(ah1, bl, accA[1][ct]);
            accA[1][ct] = mfma16(al1, bh, accA[1][ct]);
        }
        if (!diag) {
            bf16x8 ch0 = *reinterpret_cast<const bf16x8*>(&lds[8192  + rt0 * 512 + lane * 8]);
            bf16x8 ch1 = *reinterpret_cast<const bf16x8*>(&lds[8192  + rt1 * 512 + lane * 8]);
            bf16x8 cl0 = *reinterpret_cast<const bf16x8*>(&lds[12288 + rt0 * 512 + lane * 8]);
            bf16x8 cl1 = *reinterpret_cast<const bf16x8*>(&lds[12288 + rt1 * 512 + lane * 8]);
#pragma unroll
            for (int ct = 0; ct < 4; ++ct) {
                bf16x8 bh = *reinterpret_cast<const bf16x8*>(&lds[20480 + ct * 512 + lane * 8]);
                bf16x8 bl = *reinterpret_cast<const bf16x8*>(&lds[22528 + ct * 512 + lane * 8]);
                accB[0][ct] = mfma16(ch0, bh, accB[0][ct]);
                accB[0][ct] = mfma16(ch0, bl, accB[0][ct]);
                accB[0][ct] = mfma16(cl0, bh, accB[0][ct]);
                accB[1][ct] = mfma16(ch1, bh, accB[1][ct]);
                accB[1][ct] = mfma16(ch1, bl, accB[1][ct]);
                accB[1][ct] = mfma16(cl1, bh, accB[1][ct]);
            }
        }
    }

    // epilogue: per-row dot over l, reduce across the 16 col-lanes
    const float scale = diag ? 0.25f : 0.5f;
#pragma unroll
    for (int rti = 0; rti < 2; ++rti) {
#pragma unroll
        for (int r = 0; r < 4; ++r) {
            float v = 0.f;
#pragma unroll
            for (int ct = 0; ct < 4; ++ct)
                v += accA[rti][ct][r] * (diag ? accA[rti][ct][r] : accB[rti][ct][r]);
            v += __shfl_xor(v, 1, 64);
            v += __shfl_xor(v, 2, 64);
            v += __shfl_xor(v, 4, 64);
            v += __shfl_xor(v, 8, 64);
            if ((lane & 15) == 0) {
                int row = tile * 128 + (wid * 2 + rti) * 16 + (lane >> 4) * 4 + r;
                atomicAdd(&out[row], scale * v);
            }
        }
    }
}

// ===========================================================================
// Fallback fp32 path (round-1 kernels), used when ws_size is too small.
// ===========================================================================
#define BM 64
#define KC 64
#define XPAD 4

__global__ void base_kernel(const float* __restrict__ x, const float* __restrict__ bptr,
                            const float* __restrict__ w, const float* __restrict__ sv,
                            float* __restrict__ out) {
    const int row = blockIdx.x;
    const int tid = threadIdx.x;
    const float* xr = x + (size_t)row * NFEAT;
    float lin = 0.f, q = 0.f;
#pragma unroll
    for (int j = 0; j < 2; ++j) {
        int idx = j * 1024 + tid * 4;
        float4 xv = *reinterpret_cast<const float4*>(xr + idx);
        float4 wv = *reinterpret_cast<const float4*>(w + idx);
        float4 sq = *reinterpret_cast<const float4*>(sv + idx);
        lin += xv.x * wv.x + xv.y * wv.y + xv.z * wv.z + xv.w * wv.w;
        q   += xv.x * xv.x * sq.x + xv.y * xv.y * sq.y
             + xv.z * xv.z * sq.z + xv.w * xv.w * sq.w;
    }
#pragma unroll
    for (int off = 32; off >= 1; off >>= 1) {
        lin += __shfl_down(lin, off, 64);
        q   += __shfl_down(q, off, 64);
    }
    __shared__ float slin[4], sq4[4];
    const int wave = tid >> 6;
    if ((tid & 63) == 0) { slin[wave] = lin; sq4[wave] = q; }
    __syncthreads();
    if (tid == 0) {
        float L = slin[0] + slin[1] + slin[2] + slin[3];
        float Q = sq4[0] + sq4[1] + sq4[2] + sq4[3];
        out[row] = bptr[0] + L - 0.25f * Q;
    }
}

__global__ __launch_bounds__(256) void pair_kernel(const float* __restrict__ x,
                                                   const float* __restrict__ V,
                                                   float* __restrict__ out) {
    __shared__ float Xs[BM][KC + XPAD];
    __shared__ float Xt[BM][KC + XPAD];
    __shared__ float Vs[KC][NFACT];
    __shared__ float Vt[KC][NFACT];

    const int tile = blockIdx.x;
    int p = blockIdx.y;
    int s = 0;
    while (p >= NFIELD - s) { p -= NFIELD - s; ++s; }
    const int t = s + p;
    const bool diag = (s == t);

    const int tid  = threadIdx.x;
    const int lgrp = tid & 15;
    const int rgrp = tid >> 4;
    const int l0 = lgrp * 4;
    const int r0 = rgrp * 4;
    const int rowBase = tile * BM;

    float accA[4][4] = {};
    float accB[4][4] = {};

    for (int kc = 0; kc < FDIM; kc += KC) {
        __syncthreads();
#pragma unroll
        for (int it = 0; it < 4; ++it) {
            int rr = (tid >> 4) + it * 16;
            const float* gx = x + (size_t)(rowBase + rr) * NFEAT + s * FDIM + kc + (tid & 15) * 4;
            *reinterpret_cast<float4*>(&Xs[rr][(tid & 15) * 4]) =
                *reinterpret_cast<const float4*>(gx);
            if (!diag) {
                const float* gx2 = x + (size_t)(rowBase + rr) * NFEAT + t * FDIM + kc + (tid & 15) * 4;
                *reinterpret_cast<float4*>(&Xt[rr][(tid & 15) * 4]) =
                    *reinterpret_cast<const float4*>(gx2);
            }
        }
#pragma unroll
        for (int it = 0; it < 4; ++it) {
            int kk = (tid >> 4) + it * 16;
            const float* gv = V + (size_t)(s * FDIM + kc + kk) * (NFIELD * NFACT) + t * NFACT + (tid & 15) * 4;
            *reinterpret_cast<float4*>(&Vs[kk][(tid & 15) * 4]) =
                *reinterpret_cast<const float4*>(gv);
            if (!diag) {
                const float* gv2 = V + (size_t)(t * FDIM + kc + kk) * (NFIELD * NFACT) + s * NFACT + (tid & 15) * 4;
                *reinterpret_cast<float4*>(&Vt[kk][(tid & 15) * 4]) =
                    *reinterpret_cast<const float4*>(gv2);
            }
        }
        __syncthreads();

        for (int k = 0; k < KC; k += 4) {
            float xa[4][4], va[4][4];
#pragma unroll
            for (int r = 0; r < 4; ++r) {
                float4 v = *reinterpret_cast<const float4*>(&Xs[r0 + r][k]);
                xa[r][0] = v.x; xa[r][1] = v.y; xa[r][2] = v.z; xa[r][3] = v.w;
            }
#pragma unroll
            for (int kk = 0; kk < 4; ++kk) {
                float4 v = *reinterpret_cast<const float4*>(&Vs[k + kk][l0]);
                va[kk][0] = v.x; va[kk][1] = v.y; va[kk][2] = v.z; va[kk][3] = v.w;
            }
#pragma unroll
            for (int kk = 0; kk < 4; ++kk)
#pragma unroll
                for (int r = 0; r < 4; ++r)
#pragma unroll
                    for (int c = 0; c < 4; ++c)
                        accA[r][c] = fmaf(xa[r][kk], va[kk][c], accA[r][c]);

            if (!diag) {
                float xb[4][4], vb[4][4];
#pragma unroll
                for (int r = 0; r < 4; ++r) {
                    float4 v = *reinterpret_cast<const float4*>(&Xt[r0 + r][k]);
                    xb[r][0] = v.x; xb[r][1] = v.y; xb[r][2] = v.z; xb[r][3] = v.w;
                }
#pragma unroll
                for (int kk = 0; kk < 4; ++kk) {
                    float4 v = *reinterpret_cast<const float4*>(&Vt[k + kk][l0]);
                    vb[kk][0] = v.x; vb[kk][1] = v.y; vb[kk][2] = v.z; vb[kk][3] = v.w;
                }
#pragma unroll
                for (int kk = 0; kk < 4; ++kk)
#pragma unroll
                    for (int r = 0; r < 4; ++r)
#pragma unroll
                        for (int c = 0; c < 4; ++c)
                            accB[r][c] = fmaf(xb[r][kk], vb[kk][c], accB[r][c]);
            }
        }
    }

    float pr[4];
#pragma unroll
    for (int r = 0; r < 4; ++r) {
        float d = 0.f;
#pragma unroll
        for (int c = 0; c < 4; ++c)
            d += accA[r][c] * (diag ? accA[r][c] : accB[r][c]);
        pr[r] = d;
    }
#pragma unroll
    for (int off = 1; off < 16; off <<= 1) {
#pragma unroll
        for (int r = 0; r < 4; ++r)
            pr[r] += __shfl_xor(pr[r], off, 64);
    }
    if (lgrp == 0) {
        const float scale = diag ? 0.25f : 0.5f;
#pragma unroll
        for (int r = 0; r < 4; ++r)
            atomicAdd(&out[rowBase + r0 + r], scale * pr[r]);
    }
}

// ---------------------------------------------------------------------------
extern "C" void kernel_launch(void* const* d_in, const int* in_sizes, int n_in,
                              void* d_out, int out_size, void* d_ws, size_t ws_size,
                              hipStream_t stream) {
    const float* x   = (const float*)d_in[0];
    const float* b   = (const float*)d_in[1];
    const float* w   = (const float*)d_in[2];
    const float* V   = (const float*)d_in[3];
    const int*   f2f = (const int*)d_in[4];
    float* out = (float*)d_out;

    const size_t SZ_XH = 33554432;   // 8192*2048*2 B
    const size_t SZ_VH = 2097152;    // 2048*512*2 B
    const size_t NEED  = 2 * SZ_XH + 2 * SZ_VH + NFEAT * sizeof(float);

    if (ws_size >= NEED) {
        char* ws = (char*)d_ws;
        unsigned short* xh  = (unsigned short*)ws;
        unsigned short* xl  = (unsigned short*)(ws + SZ_XH);
        unsigned short* vhp = (unsigned short*)(ws + 2 * SZ_XH);
        unsigned short* vlp = (unsigned short*)(ws + 2 * SZ_XH + SZ_VH);
        float* sv = (float*)(ws + 2 * SZ_XH + 2 * SZ_VH);

        sv_kernel<<<(NFEAT + 255) / 256, 256, 0, stream>>>(V, f2f, sv);
        init_out<<<(BATCH + 255) / 256, 256, 0, stream>>>(b, out);
        convert_v<<<131072 / 256, 256, 0, stream>>>(V, vhp, vlp);
        convert_x_fused<<<2097152 / 256, 256, 0, stream>>>(x, w, sv, xh, xl, out);
        dim3 grid(BATCH / 128, NPAIR);
        pair_mfma<<<grid, 256, 0, stream>>>(xh, xl, vhp, vlp, out);
    } else {
        float* sv = (float*)d_ws;
        sv_kernel<<<(NFEAT + 255) / 256, 256, 0, stream>>>(V, f2f, sv);
        base_kernel<<<BATCH, 256, 0, stream>>>(x, b, w, sv, out);
        dim3 grid(BATCH / BM, NPAIR);
        pair_kernel<<<grid, 256, 0, stream>>>(x, V, out);
    }
}